// Round 6
// baseline (515.396 us; speedup 1.0000x reference)
//
#include <hip/hip_runtime.h>
#include <hip/hip_bf16.h>

#define BATCH 64
#define SEQ   256
#define EMB   64
#define QKVD  64
#define KD    8192      // L*EMB
#define ND    8192      // L*QKV
#define SEQD  16384     // SEQ*EMB (per-batch x row)
#define BK    128
#define NT    (KD / BK)   // 64 k-tiles

typedef __attribute__((ext_vector_type(8))) short bf16x8;
typedef __attribute__((ext_vector_type(4))) float f32x4;

struct WArgs { const float* W[6]; const float* b[6]; };

// branchless round-to-nearest-even fp32 -> bf16 bits (inputs are finite)
__device__ __forceinline__ short f2bf(float f) {
    unsigned u = __builtin_bit_cast(unsigned, f);
    u += 0x7fffu + ((u >> 16) & 1u);
    return (short)(u >> 16);
}

// async global->LDS, 16B per lane; LDS dest = wave-uniform base + lane*16
__device__ __forceinline__ void gl16(const void* g, void* l) {
    __builtin_amdgcn_global_load_lds(
        (const __attribute__((address_space(1))) void*)g,
        (__attribute__((address_space(3))) void*)l, 16, 0, 0);
}

__device__ __forceinline__ void barrier_fenced() {
    asm volatile("" ::: "memory");
    __builtin_amdgcn_s_barrier();
    asm volatile("" ::: "memory");
}

// ---------------- kernel 1: x fp32 -> bf16 ----------------------------------
__global__ __launch_bounds__(256)
void cvt_x_kernel(const float* __restrict__ x, short* __restrict__ xb) {
    const int i = (blockIdx.x * 256 + threadIdx.x) * 4;
    float4 v = *reinterpret_cast<const float4*>(x + i);
    short4 o;
    o.x = f2bf(v.x); o.y = f2bf(v.y); o.z = f2bf(v.z); o.w = f2bf(v.w);
    *reinterpret_cast<short4*>(xb + i) = o;
}

// ---------------- kernel 2: QKV projections ---------------------------------
// C[m][n] = sum_k xs[m,k] * W[n,k] + b[n], per gi in [0,6)
// Block tile 64m x 64n, BK=128, 4 waves (wave tile 64m x 16n).
// W (the compulsory HBM stream): gl_lds, double-buffered, 512B/row per issue,
//   issue-early + counted vmcnt(8) -> next tile always in flight over compute.
// A (L2-resident bf16 xs): direct global->VGPR fragments, no LDS path.
// Each wave stages exactly the 16 W rows it computes -> ONE barrier per tile
// (WAR fence before buffer overwrite), no pre-compute barrier needed.
__global__ __launch_bounds__(256, 2)
void qkv_gemm_kernel(const short* __restrict__ xb, WArgs wa,
                     float* __restrict__ qkv) {
    __shared__ __attribute__((aligned(16))) float W_lds[2][64 * BK]; // 2x32KB

    // bijective XCD swizzle: 768 tiles, XCD x gets logical [x*96, x*96+96)
    const int bid     = blockIdx.x;
    const int logical = (bid & 7) * 96 + (bid >> 3);
    const int gi      = logical >> 7;          // 0..5
    const int n0      = (logical & 127) * 64;  // n-tile origin
    const int g       = gi / 3;

    const int wv = threadIdx.x >> 6;
    const int ln = threadIdx.x & 63;
    const int r  = ln & 15;           // n within wave tile / frag index
    const int kb = ln >> 4;           // k sub-block (8 elems)

    const float* __restrict__ Wg = wa.W[gi];

    // staging lane constants: issue j covers rows 2j,2j+1 (512B each)
    const int s_rh = ln >> 5;         // row within pair
    const int s_c  = ln & 31;         // phys 16B chunk within 512B row

    f32x4 acc0 = {0.f, 0.f, 0.f, 0.f};
    f32x4 acc1 = acc0, acc2 = acc0, acc3 = acc0;

    auto stage = [&](int t, int buf) {
        const float* Ws = Wg + (size_t)n0 * KD + t * BK;
        #pragma unroll
        for (int jj = 0; jj < 8; ++jj) {          // 8 x 1KB per wave
            const int j   = wv * 8 + jj;          // rows 2j, 2j+1 (own rows)
            const int row = 2 * j + s_rh;
            const int c   = s_c ^ (row & 7);      // source pre-swizzle (#21)
            gl16(Ws + (size_t)row * KD + c * 4,
                 (char*)&W_lds[buf][0] + j * 1024);
        }
    };

    auto compute = [&](int buf, int t) {
        const float* Wb = &W_lds[buf][0];
        const short* Ag = xb + g * KD + t * BK + kb * 8;
        const int wrow = wv * 16 + r;
        const float* Wrow = Wb + wrow * BK;
        const int sw = (wrow & 7);
        #pragma unroll
        for (int kk = 0; kk < 4; ++kk) {
            const int c0 = kk * 8 + kb * 2;
            f32x4 w0 = *(const f32x4*)(Wrow + ((c0    ) ^ sw) * 4);
            f32x4 w1 = *(const f32x4*)(Wrow + ((c0 + 1) ^ sw) * 4);
            bf16x8 bb;
            bb[0] = f2bf(w0[0]); bb[1] = f2bf(w0[1]); bb[2] = f2bf(w0[2]); bb[3] = f2bf(w0[3]);
            bb[4] = f2bf(w1[0]); bb[5] = f2bf(w1[1]); bb[6] = f2bf(w1[2]); bb[7] = f2bf(w1[3]);
            const short* ak = Ag + kk * 32;
            const bf16x8 a0 = *(const bf16x8*)(ak + (size_t)(r)      * SEQD);
            const bf16x8 a1 = *(const bf16x8*)(ak + (size_t)(r + 16) * SEQD);
            const bf16x8 a2 = *(const bf16x8*)(ak + (size_t)(r + 32) * SEQD);
            const bf16x8 a3 = *(const bf16x8*)(ak + (size_t)(r + 48) * SEQD);
            acc0 = __builtin_amdgcn_mfma_f32_16x16x32_bf16(a0, bb, acc0, 0, 0, 0);
            acc1 = __builtin_amdgcn_mfma_f32_16x16x32_bf16(a1, bb, acc1, 0, 0, 0);
            acc2 = __builtin_amdgcn_mfma_f32_16x16x32_bf16(a2, bb, acc2, 0, 0, 0);
            acc3 = __builtin_amdgcn_mfma_f32_16x16x32_bf16(a3, bb, acc3, 0, 0, 0);
        }
    };

    stage(0, 0);
    for (int t = 0; t < NT - 1; ++t) {
        stage(t + 1, (t + 1) & 1);                      // issue BEFORE compute
        asm volatile("s_waitcnt vmcnt(8)" ::: "memory"); // own tile-t W landed;
                                                         // tile t+1 in flight
        compute(t & 1, t);
        barrier_fenced();        // all reads of buf[t&1] done before overwrite
    }
    asm volatile("s_waitcnt vmcnt(0)" ::: "memory");
    compute((NT - 1) & 1, NT - 1);

    // D layout (m89): col = lane&15, row = (lane>>4)*4 + reg
    const int nbr = n0 + wv * 16 + r;
    const float bias = wa.b[gi][nbr];
    float* orow = qkv + (size_t)gi * (BATCH * ND) + nbr;
    #pragma unroll
    for (int reg = 0; reg < 4; ++reg) {
        const int m = kb * 4 + reg;
        orow[(size_t)(m)      * ND] = acc0[reg] + bias;
        orow[(size_t)(m + 16) * ND] = acc1[reg] + bias;
        orow[(size_t)(m + 32) * ND] = acc2[reg] + bias;
        orow[(size_t)(m + 48) * ND] = acc3[reg] + bias;
    }
}

// ---------------- kernel 3: attention per (batch, group) -------------------
// scores[i][j] = Q[i,:]·K[j,:]; softmax over i (query axis); Z = attn·V; ×0.125
__global__ __launch_bounds__(256)
void attn_kernel(const float* __restrict__ qkv, float* __restrict__ out) {
    __shared__ float Ql[128 * 65];   // Q, then reused for V
    __shared__ float Kl[128 * 65];
    __shared__ float Sc[128 * 129];
    __shared__ float Pm[256];
    __shared__ float Ps[256];
    __shared__ float Rden[128];

    const int b = blockIdx.x;
    const int g = blockIdx.y;
    const int t = threadIdx.x;

    const float* __restrict__ Qg = qkv + ((size_t)(3 * g + 0) * BATCH + b) * ND;
    const float* __restrict__ Kg = qkv + ((size_t)(3 * g + 1) * BATCH + b) * ND;
    const float* __restrict__ Vg = qkv + ((size_t)(3 * g + 2) * BATCH + b) * ND;

    for (int e = t; e < 8192; e += 256) {
        const int i = e >> 6, k = e & 63;
        Ql[i * 65 + k] = Qg[e];
        Kl[i * 65 + k] = Kg[e];
    }
    __syncthreads();

    // scores: 8x8 register tile per thread
    {
        const int i0 = (t >> 4) * 8;
        const int j0 = (t & 15) * 8;
        float s[8][8];
        #pragma unroll
        for (int rr = 0; rr < 8; ++rr)
            #pragma unroll
            for (int cc = 0; cc < 8; ++cc) s[rr][cc] = 0.f;
        for (int k = 0; k < 64; ++k) {
            float qv[8], kv[8];
            #pragma unroll
            for (int rr = 0; rr < 8; ++rr) qv[rr] = Ql[(i0 + rr) * 65 + k];
            #pragma unroll
            for (int cc = 0; cc < 8; ++cc) kv[cc] = Kl[(j0 + cc) * 65 + k];
            #pragma unroll
            for (int rr = 0; rr < 8; ++rr)
                #pragma unroll
                for (int cc = 0; cc < 8; ++cc)
                    s[rr][cc] = fmaf(qv[rr], kv[cc], s[rr][cc]);
        }
        #pragma unroll
        for (int rr = 0; rr < 8; ++rr)
            #pragma unroll
            for (int cc = 0; cc < 8; ++cc)
                Sc[(i0 + rr) * 129 + (j0 + cc)] = s[rr][cc];
    }
    __syncthreads();

    // V fill (Q dead) + per-column partial max; column j, half h
    const int j = t & 127, h = t >> 7;
    {
        for (int e = t; e < 8192; e += 256) {
            const int i = e >> 6, k = e & 63;
            Ql[i * 65 + k] = Vg[e];
        }
        float m = -3.0e38f;
        for (int i = h * 64; i < h * 64 + 64; ++i)
            m = fmaxf(m, Sc[i * 129 + j]);
        Pm[h * 128 + j] = m;
    }
    __syncthreads();
    {
        const float m = fmaxf(Pm[j], Pm[128 + j]);
        float sum = 0.f;
        for (int i = h * 64; i < h * 64 + 64; ++i) {
            const float e = __expf(Sc[i * 129 + j] - m);
            Sc[i * 129 + j] = e;
            sum += e;
        }
        Ps[h * 128 + j] = sum;
    }
    __syncthreads();
    if (t < 128) Rden[t] = 1.0f / (Ps[t] + Ps[128 + t]);
    __syncthreads();

    // PV: 8 rows x 4 cols per thread
    {
        const int i0 = (t >> 4) * 8;
        const int k0 = (t & 15) * 4;
        float z[8][4];
        #pragma unroll
        for (int rr = 0; rr < 8; ++rr)
            #pragma unroll
            for (int cc = 0; cc < 4; ++cc) z[rr][cc] = 0.f;
        for (int jj = 0; jj < 128; ++jj) {
            const float rd = Rden[jj];
            float av[8], vv[4];
            #pragma unroll
            for (int rr = 0; rr < 8; ++rr) av[rr] = Sc[(i0 + rr) * 129 + jj] * rd;
            #pragma unroll
            for (int cc = 0; cc < 4; ++cc) vv[cc] = Ql[jj * 65 + k0 + cc];
            #pragma unroll
            for (int rr = 0; rr < 8; ++rr)
                #pragma unroll
                for (int cc = 0; cc < 4; ++cc)
                    z[rr][cc] = fmaf(av[rr], vv[cc], z[rr][cc]);
        }
        float* op = out + (size_t)b * (SEQ * QKVD) + (size_t)(g * 128) * QKVD + k0;
        #pragma unroll
        for (int rr = 0; rr < 8; ++rr) {
            float4 o;
            o.x = z[rr][0] * 0.125f; o.y = z[rr][1] * 0.125f;
            o.z = z[rr][2] * 0.125f; o.w = z[rr][3] * 0.125f;
            *reinterpret_cast<float4*>(op + (size_t)(i0 + rr) * QKVD) = o;
        }
    }
}

// ---------------- launcher --------------------------------------------------
extern "C" void kernel_launch(void* const* d_in, const int* in_sizes, int n_in,
                              void* d_out, int out_size, void* d_ws, size_t ws_size,
                              hipStream_t stream) {
    const float* x = (const float*)d_in[0];
    WArgs wa;
    for (int g = 0; g < 2; ++g)
        for (int q = 0; q < 3; ++q) {
            wa.W[g * 3 + q] = (const float*)d_in[1 + g * 6 + q * 2];
            wa.b[g * 3 + q] = (const float*)d_in[2 + g * 6 + q * 2];
        }

    short* xb  = (short*)d_ws;                                      // 2 MiB
    float* qkv = (float*)((char*)d_ws + (size_t)4 * 1024 * 1024);   // 12.6 MiB

    cvt_x_kernel<<<dim3(1024), dim3(256), 0, stream>>>(x, xb);
    qkv_gemm_kernel<<<dim3(768), dim3(256), 0, stream>>>(xb, wa, qkv);
    attn_kernel<<<dim3(BATCH, 2), dim3(256), 0, stream>>>(qkv, (float*)d_out);
}

// Round 7
// 373.123 us; speedup vs baseline: 1.3813x; 1.3813x over previous
//
#include <hip/hip_runtime.h>
#include <hip/hip_bf16.h>

#define BATCH 64
#define SEQ   256
#define EMB   64
#define QKVD  64
#define KD    8192      // L*EMB
#define ND    8192      // L*QKV
#define SEQD  16384     // SEQ*EMB (per-batch x row)
#define BKH   32        // half-tile K extent
#define NH    (KD / BKH)   // 256 half-tiles

typedef __attribute__((ext_vector_type(8))) short bf16x8;
typedef __attribute__((ext_vector_type(4))) float f32x4;

struct WArgs { const float* W[6]; const float* b[6]; };

// branchless round-to-nearest-even fp32 -> bf16 bits (inputs are finite)
__device__ __forceinline__ short f2bf(float f) {
    unsigned u = __builtin_bit_cast(unsigned, f);
    u += 0x7fffu + ((u >> 16) & 1u);
    return (short)(u >> 16);
}

// async global->LDS, 16B per lane; LDS dest = wave-uniform base + lane*16
__device__ __forceinline__ void gl16(const void* g, void* l) {
    __builtin_amdgcn_global_load_lds(
        (const __attribute__((address_space(1))) void*)g,
        (__attribute__((address_space(3))) void*)l, 16, 0, 0);
}

__device__ __forceinline__ void barrier_fenced() {
    asm volatile("" ::: "memory");
    __builtin_amdgcn_s_barrier();
    asm volatile("" ::: "memory");
}

// ---------------- kernel 1: x fp32 -> bf16 ----------------------------------
__global__ __launch_bounds__(256)
void cvt_x_kernel(const float* __restrict__ x, short* __restrict__ xb) {
    const int i = (blockIdx.x * 256 + threadIdx.x) * 4;
    float4 v = *reinterpret_cast<const float4*>(x + i);
    short4 o;
    o.x = f2bf(v.x); o.y = f2bf(v.y); o.z = f2bf(v.z); o.w = f2bf(v.w);
    *reinterpret_cast<short4*>(xb + i) = o;
}

// ---------------- kernel 2: QKV projections ---------------------------------
// C[m][n] = sum_k xs[m,k] * W[n,k] + b[n], per gi in [0,6)
// Block tile 64m x 64n, 4 waves (wave tile 64m x 16n).
// Ring of 4 half-tile slots (K=32 each): A 4KB + W 8KB per slot = 48KB LDS.
// Depth-3 halves in flight; per half-iter: vmcnt(6) -> barrier -> compute(h)
// -> barrier -> stage(h+3). All VMEM in the loop is gl_lds (uniform ledger).
__global__ __launch_bounds__(256, 3)
void qkv_gemm_kernel(const short* __restrict__ xb, WArgs wa,
                     float* __restrict__ qkv) {
    __shared__ __attribute__((aligned(16))) short A_lds[4][64 * BKH]; // 4x4KB
    __shared__ __attribute__((aligned(16))) float W_lds[4][64 * BKH]; // 4x8KB

    // bijective XCD swizzle: 768 tiles, XCD x gets logical [x*96, x*96+96)
    const int bid     = blockIdx.x;
    const int logical = (bid & 7) * 96 + (bid >> 3);
    const int gi      = logical >> 7;          // 0..5
    const int n0      = (logical & 127) * 64;  // n-tile origin
    const int g       = gi / 3;

    const int wv = threadIdx.x >> 6;
    const int ln = threadIdx.x & 63;
    const int r  = ln & 15;           // n within wave tile / frag index
    const int kb = ln >> 4;           // k sub-block of 8 within 32 (0..3)

    const float* __restrict__ Wg = wa.W[gi];
    const short* __restrict__ Ag = xb + g * KD;

    // A staging: 1 issue/wave = 16 rows x 32 cols bf16 (64B/row)
    const int a_row = ln >> 2;                    // 0..15 (row in group)
    const int a_cs  = (ln & 3) ^ (a_row & 3);     // pre-swizzled source chunk
    // W staging: 2 issues/wave = 8 rows x 32 cols f32 (128B/row) each
    const int w_row = ln >> 3;                    // 0..7
    const int w_c   = ln & 7;                     // linear 16B chunk in row

    f32x4 acc0 = {0.f, 0.f, 0.f, 0.f};
    f32x4 acc1 = acc0, acc2 = acc0, acc3 = acc0;

    auto stage = [&](int h) {
        const int s = h & 3;
        {   // A rows wv*16 .. wv*16+15
            const int row = wv * 16 + a_row;
            gl16(Ag + (size_t)row * SEQD + h * BKH + a_cs * 8,
                 (char*)&A_lds[s][0] + wv * 1024);
        }
        #pragma unroll
        for (int jj = 0; jj < 2; ++jj) {          // wave's OWN 16 W rows
            const int row = wv * 16 + jj * 8 + w_row;
            const int cs  = w_c ^ (row & 7);      // pre-swizzle (rule #21)
            gl16(Wg + (size_t)(n0 + row) * KD + h * BKH + cs * 4,
                 (char*)&W_lds[s][0] + (wv * 2 + jj) * 1024);
        }
    };

    auto compute = [&](int h) {
        const int s = h & 3;
        const short* Ab = &A_lds[s][0];
        const float* Wb = &W_lds[s][0];
        const int wrow = wv * 16 + r;
        // W: linear row-major [64][32] f32, chunk c holds global chunk c^(row&7)
        f32x4 w0 = *(const f32x4*)(Wb + wrow * BKH + (((kb * 2)     ^ (wrow & 7)) * 4));
        f32x4 w1 = *(const f32x4*)(Wb + wrow * BKH + (((kb * 2 + 1) ^ (wrow & 7)) * 4));
        bf16x8 bb;
        bb[0] = f2bf(w0[0]); bb[1] = f2bf(w0[1]); bb[2] = f2bf(w0[2]); bb[3] = f2bf(w0[3]);
        bb[4] = f2bf(w1[0]); bb[5] = f2bf(w1[1]); bb[6] = f2bf(w1[2]); bb[7] = f2bf(w1[3]);
        // A: linear row-major [64][32] bf16, chunk c holds global chunk c^(row&3)
        const int ac = (kb ^ (r & 3)) * 8;
        const bf16x8 a0 = *(const bf16x8*)(Ab + (r)      * BKH + ac);
        const bf16x8 a1 = *(const bf16x8*)(Ab + (r + 16) * BKH + ac);
        const bf16x8 a2 = *(const bf16x8*)(Ab + (r + 32) * BKH + ac);
        const bf16x8 a3 = *(const bf16x8*)(Ab + (r + 48) * BKH + ac);
        acc0 = __builtin_amdgcn_mfma_f32_16x16x32_bf16(a0, bb, acc0, 0, 0, 0);
        acc1 = __builtin_amdgcn_mfma_f32_16x16x32_bf16(a1, bb, acc1, 0, 0, 0);
        acc2 = __builtin_amdgcn_mfma_f32_16x16x32_bf16(a2, bb, acc2, 0, 0, 0);
        acc3 = __builtin_amdgcn_mfma_f32_16x16x32_bf16(a3, bb, acc3, 0, 0, 0);
    };

    // prologue: 3 halves in flight (9 issues/wave)
    stage(0); stage(1); stage(2);

    for (int h = 0; h < NH - 3; ++h) {
        asm volatile("s_waitcnt vmcnt(6)" ::: "memory"); // own half-h landed;
                                                         // h+1,h+2 in flight
        barrier_fenced();            // all waves' half-h fully in LDS
        compute(h);
        barrier_fenced();            // WAR: slot (h+3)&3 free to overwrite
        stage(h + 3);
    }
    // tail: h = NH-3, NH-2, NH-1 (no more stages)
    asm volatile("s_waitcnt vmcnt(6)" ::: "memory");
    barrier_fenced();
    compute(NH - 3);
    asm volatile("s_waitcnt vmcnt(3)" ::: "memory");
    barrier_fenced();
    compute(NH - 2);
    asm volatile("s_waitcnt vmcnt(0)" ::: "memory");
    barrier_fenced();
    compute(NH - 1);

    // D layout (m89): col = lane&15, row = (lane>>4)*4 + reg
    const int nbr = n0 + wv * 16 + r;
    const float bias = wa.b[gi][nbr];
    float* orow = qkv + (size_t)gi * (BATCH * ND) + nbr;
    #pragma unroll
    for (int reg = 0; reg < 4; ++reg) {
        const int m = kb * 4 + reg;
        orow[(size_t)(m)      * ND] = acc0[reg] + bias;
        orow[(size_t)(m + 16) * ND] = acc1[reg] + bias;
        orow[(size_t)(m + 32) * ND] = acc2[reg] + bias;
        orow[(size_t)(m + 48) * ND] = acc3[reg] + bias;
    }
}

// ---------------- kernel 3: attention per (batch, group) -------------------
// scores[i][j] = Q[i,:]·K[j,:]; softmax over i (query axis); Z = attn·V; ×0.125
__global__ __launch_bounds__(256)
void attn_kernel(const float* __restrict__ qkv, float* __restrict__ out) {
    __shared__ float Ql[128 * 65];   // Q, then reused for V
    __shared__ float Kl[128 * 65];
    __shared__ float Sc[128 * 129];
    __shared__ float Pm[256];
    __shared__ float Ps[256];
    __shared__ float Rden[128];

    const int b = blockIdx.x;
    const int g = blockIdx.y;
    const int t = threadIdx.x;

    const float* __restrict__ Qg = qkv + ((size_t)(3 * g + 0) * BATCH + b) * ND;
    const float* __restrict__ Kg = qkv + ((size_t)(3 * g + 1) * BATCH + b) * ND;
    const float* __restrict__ Vg = qkv + ((size_t)(3 * g + 2) * BATCH + b) * ND;

    for (int e = t; e < 8192; e += 256) {
        const int i = e >> 6, k = e & 63;
        Ql[i * 65 + k] = Qg[e];
        Kl[i * 65 + k] = Kg[e];
    }
    __syncthreads();

    // scores: 8x8 register tile per thread
    {
        const int i0 = (t >> 4) * 8;
        const int j0 = (t & 15) * 8;
        float s[8][8];
        #pragma unroll
        for (int rr = 0; rr < 8; ++rr)
            #pragma unroll
            for (int cc = 0; cc < 8; ++cc) s[rr][cc] = 0.f;
        for (int k = 0; k < 64; ++k) {
            float qv[8], kv[8];
            #pragma unroll
            for (int rr = 0; rr < 8; ++rr) qv[rr] = Ql[(i0 + rr) * 65 + k];
            #pragma unroll
            for (int cc = 0; cc < 8; ++cc) kv[cc] = Kl[(j0 + cc) * 65 + k];
            #pragma unroll
            for (int rr = 0; rr < 8; ++rr)
                #pragma unroll
                for (int cc = 0; cc < 8; ++cc)
                    s[rr][cc] = fmaf(qv[rr], kv[cc], s[rr][cc]);
        }
        #pragma unroll
        for (int rr = 0; rr < 8; ++rr)
            #pragma unroll
            for (int cc = 0; cc < 8; ++cc)
                Sc[(i0 + rr) * 129 + (j0 + cc)] = s[rr][cc];
    }
    __syncthreads();

    // V fill (Q dead) + per-column partial max; column j, half h
    const int j = t & 127, h = t >> 7;
    {
        for (int e = t; e < 8192; e += 256) {
            const int i = e >> 6, k = e & 63;
            Ql[i * 65 + k] = Vg[e];
        }
        float m = -3.0e38f;
        for (int i = h * 64; i < h * 64 + 64; ++i)
            m = fmaxf(m, Sc[i * 129 + j]);
        Pm[h * 128 + j] = m;
    }
    __syncthreads();
    {
        const float m = fmaxf(Pm[j], Pm[128 + j]);
        float sum = 0.f;
        for (int i = h * 64; i < h * 64 + 64; ++i) {
            const float e = __expf(Sc[i * 129 + j] - m);
            Sc[i * 129 + j] = e;
            sum += e;
        }
        Ps[h * 128 + j] = sum;
    }
    __syncthreads();
    if (t < 128) Rden[t] = 1.0f / (Ps[t] + Ps[128 + t]);
    __syncthreads();

    // PV: 8 rows x 4 cols per thread
    {
        const int i0 = (t >> 4) * 8;
        const int k0 = (t & 15) * 4;
        float z[8][4];
        #pragma unroll
        for (int rr = 0; rr < 8; ++rr)
            #pragma unroll
            for (int cc = 0; cc < 4; ++cc) z[rr][cc] = 0.f;
        for (int jj = 0; jj < 128; ++jj) {
            const float rd = Rden[jj];
            float av[8], vv[4];
            #pragma unroll
            for (int rr = 0; rr < 8; ++rr) av[rr] = Sc[(i0 + rr) * 129 + jj] * rd;
            #pragma unroll
            for (int cc = 0; cc < 4; ++cc) vv[cc] = Ql[jj * 65 + k0 + cc];
            #pragma unroll
            for (int rr = 0; rr < 8; ++rr)
                #pragma unroll
                for (int cc = 0; cc < 4; ++cc)
                    z[rr][cc] = fmaf(av[rr], vv[cc], z[rr][cc]);
        }
        float* op = out + (size_t)b * (SEQ * QKVD) + (size_t)(g * 128) * QKVD + k0;
        #pragma unroll
        for (int rr = 0; rr < 8; ++rr) {
            float4 o;
            o.x = z[rr][0] * 0.125f; o.y = z[rr][1] * 0.125f;
            o.z = z[rr][2] * 0.125f; o.w = z[rr][3] * 0.125f;
            *reinterpret_cast<float4*>(op + (size_t)(i0 + rr) * QKVD) = o;
        }
    }
}

// ---------------- launcher --------------------------------------------------
extern "C" void kernel_launch(void* const* d_in, const int* in_sizes, int n_in,
                              void* d_out, int out_size, void* d_ws, size_t ws_size,
                              hipStream_t stream) {
    const float* x = (const float*)d_in[0];
    WArgs wa;
    for (int g = 0; g < 2; ++g)
        for (int q = 0; q < 3; ++q) {
            wa.W[g * 3 + q] = (const float*)d_in[1 + g * 6 + q * 2];
            wa.b[g * 3 + q] = (const float*)d_in[2 + g * 6 + q * 2];
        }

    short* xb  = (short*)d_ws;                                      // 2 MiB
    float* qkv = (float*)((char*)d_ws + (size_t)4 * 1024 * 1024);   // 12.6 MiB

    cvt_x_kernel<<<dim3(1024), dim3(256), 0, stream>>>(x, xb);
    qkv_gemm_kernel<<<dim3(768), dim3(256), 0, stream>>>(xb, wa, qkv);
    attn_kernel<<<dim3(BATCH, 2), dim3(256), 0, stream>>>(qkv, (float*)d_out);
}